// Round 2
// 1134.660 us; speedup vs baseline: 1.2354x; 1.2354x over previous
//
#include <hip/hip_runtime.h>
#include <cstdint>
#include <cstddef>

// ---------------------------------------------------------------------------
// OrderedMemoryDecoder (DEPTH=14, B=8, H=1024, V=32000) for gfx950.
// R3b: R3 with k_wct compile fix (stray out-of-scope reference removed).
// k_gemm epilogue rewrite (max-first reduce, native exp2, nt stores);
// k_cellg K-split x4; k_ln2 shuffle reductions; vectorized W_out transpose.
// ---------------------------------------------------------------------------

typedef __attribute__((ext_vector_type(4))) float   f4;
typedef __attribute__((ext_vector_type(4))) float   f32x4;
typedef __attribute__((ext_vector_type(8))) __bf16  bf16x8;
typedef __attribute__((ext_vector_type(4))) unsigned short us4;
typedef __attribute__((ext_vector_type(8))) unsigned short us8;

constexpr int DEPTH = 14;
constexpr int Bb = 8;
constexpr int Hd = 1024;
constexpr int Vv = 32000;
constexpr int NT = Vv / 128;   // 250 N-tiles in big GEMM
constexpr int MAXT = 512;
constexpr int MAXS = 4096;
constexpr int MAXP = 32;
constexpr float L2E = 1.44269504088896340736f;

struct SB {
  int lvlOff[DEPTH + 1];
  int lvlK[DEPTH];
  int len[MAXT];
  int lch[MAXT], rch[MAXT];
  int parCnt[DEPTH];
  int parRows[DEPTH][MAXP];
  int T;
  int nS;
  int sOut[MAXS], sIn[MAXS];
  int nStart, nEnd;
  int startIdx[16], endIdx[16];
};

constexpr int ceil75(int L) {
  constexpr int t[14] = {0, 1, 2, 3, 3, 4, 4, 5, 5, 6, 6, 7, 7, 7};
  return t[L];
}

constexpr SB build() {
  SB s{};
  for (int i = 0; i < MAXT; i++) { s.lch[i] = -1; s.rch[i] = -1; }
  s.lvlOff[0] = 0; s.lvlK[0] = 1; s.len[0] = DEPTH;
  for (int l = 0; l < DEPTH - 1; l++) {
    int off = s.lvlOff[l], K = s.lvlK[l];
    int nxt = off + K, cnt = 0;
    for (int i = 0; i < K; i++) {
      int g = off + i;
      if (s.len[g] > 1) {
        int gl = nxt + 2 * cnt, gr = gl + 1;
        s.lch[g] = gl; s.rch[g] = gr;
        s.len[gl] = ceil75(s.len[g] - 1);
        s.len[gr] = s.len[g] - 1;
        s.parRows[l][cnt] = g;
        cnt++;
      }
    }
    s.parCnt[l] = cnt;
    s.lvlOff[l + 1] = nxt;
    s.lvlK[l + 1] = 2 * cnt;
  }
  s.T = s.lvlOff[DEPTH - 1] + s.lvlK[DEPTH - 1];
  s.nS = 0;
  for (int l = DEPTH - 2; l >= 0; l--) {
    for (int pi = 0; pi < s.parCnt[l]; pi++) {
      int g = s.parRows[l][pi];
      for (int u = s.lch[g]; u != -1; u = s.rch[u])
        for (int v = s.rch[g]; v != -1; v = s.lch[v]) {
          s.sOut[s.nS] = u; s.sIn[s.nS] = v; s.nS++;
        }
    }
  }
  s.nStart = 0;
  for (int u = 0; u != -1; u = s.lch[u]) s.startIdx[s.nStart++] = u;
  s.nEnd = 0;
  for (int u = 0; u != -1; u = s.rch[u]) s.endIdx[s.nEnd++] = u;
  return s;
}

constexpr SB HS = build();
__device__ const SB DS = build();

struct PR { int v[MAXP]; };

__device__ __forceinline__ unsigned short f2bf(float f) {
  union { float f; unsigned u; } v; v.f = f;
  unsigned r = v.u + 0x7fffu + ((v.u >> 16) & 1u);  // RNE
  return (unsigned short)(r >> 16);
}

// --------------------------- W_out -> bf16, transposed ----------------------
// Tile 64(K) x 128(N). f4 reads (512B/row-wave), 16B bf16 writes
// (128B contiguous per n-row across 8 lanes).
__global__ void k_wout_t(const float* __restrict__ Wout,
                         unsigned short* __restrict__ Wt) {
  __shared__ float t[64][129];
  int tid = threadIdx.x;
  int n0 = blockIdx.x * 128, k0 = blockIdx.y * 64;
#pragma unroll
  for (int i = 0; i < 8; i++) {
    int k = (tid >> 5) + 8 * i;
    int c = (tid & 31) * 4;
    f4 v = *(const f4*)&Wout[(size_t)(k0 + k) * Vv + n0 + c];
    t[k][c] = v.x; t[k][c + 1] = v.y; t[k][c + 2] = v.z; t[k][c + 3] = v.w;
  }
  __syncthreads();
#pragma unroll
  for (int pass = 0; pass < 4; pass++) {
    int n = (tid >> 3) + 32 * pass;   // lanes 0-7 cover 64 k of one n-row
    int ks = (tid & 7) * 8;
    us8 o;
#pragma unroll
    for (int q = 0; q < 8; q++) o[q] = f2bf(t[ks + q][n]);
    *(us8*)&Wt[(size_t)(n0 + n) * Hd + k0 + ks] = o;
  }
}

// --------------- W_cell[:1024,:] -> bf16, transposed [2048][1024] -----------
__global__ void k_wct(const float* __restrict__ Wc,
                      unsigned short* __restrict__ Wct) {
  __shared__ float t[32][33];
  int tx = threadIdx.x, ty = threadIdx.y;
  int n0 = blockIdx.x * 32, k0 = blockIdx.y * 32;
  for (int i = 0; i < 4; i++)
    t[ty + 8 * i][tx] = Wc[(size_t)(k0 + ty + 8 * i) * 2048 + n0 + tx];
  __syncthreads();
  for (int i = 0; i < 4; i++)
    Wct[(size_t)(n0 + ty + 8 * i) * Hd + k0 + tx] = f2bf(t[tx][ty + 8 * i]);
}

// ------------------------------ g and h0 ------------------------------------
__global__ void k_init(const float* __restrict__ x, const float* __restrict__ Wg,
                       const float* __restrict__ bg, const float* __restrict__ Win,
                       const float* __restrict__ bin, float* __restrict__ gbuf,
                       float* __restrict__ hidd, unsigned short* __restrict__ hiddb) {
  __shared__ float xs[Bb * Hd];
  __shared__ float part[Bb][128];
  int tid = threadIdx.x;
  int mat = blockIdx.y;
  const float* W = mat ? Win : Wg;
  const float* bias = mat ? bin : bg;
  for (int i = tid; i < Bb * Hd; i += 256) xs[i] = x[i];
  __syncthreads();
  int c = tid & 127, kh = tid >> 7;
  int col = blockIdx.x * 128 + c;
  float acc[Bb];
#pragma unroll
  for (int b = 0; b < Bb; b++) acc[b] = 0.f;
  for (int k = kh * 512; k < kh * 512 + 512; k++) {
    float w = W[(size_t)k * Hd + col];
#pragma unroll
    for (int b = 0; b < Bb; b++) acc[b] += xs[b * Hd + k] * w;
  }
  if (kh == 1)
    for (int b = 0; b < Bb; b++) part[b][c] = acc[b];
  __syncthreads();
  if (kh == 0) {
    for (int b = 0; b < Bb; b++) {
      float v = acc[b] + part[b][c] + bias[col];
      if (mat == 0) gbuf[b * Hd + col] = v;
      else { hidd[(size_t)b * Hd + col] = v; hiddb[(size_t)b * Hd + col] = f2bf(v); }
    }
  }
}

// --------------------- gW = g @ W_cell[1024:,:] + b_cell --------------------
__global__ void k_gw(const float* __restrict__ gbuf, const float* __restrict__ Wc,
                     const float* __restrict__ bc, float* __restrict__ gW) {
  __shared__ float xs[Bb * Hd];
  __shared__ float part[Bb][128];
  int tid = threadIdx.x;
  for (int i = tid; i < Bb * Hd; i += 256) xs[i] = gbuf[i];
  __syncthreads();
  int c = tid & 127, kh = tid >> 7;
  int col = blockIdx.x * 128 + c;
  float acc[Bb];
#pragma unroll
  for (int b = 0; b < Bb; b++) acc[b] = 0.f;
  for (int k = kh * 512; k < kh * 512 + 512; k++) {
    float w = Wc[(size_t)(Hd + k) * 2048 + col];
#pragma unroll
    for (int b = 0; b < Bb; b++) acc[b] += xs[b * Hd + k] * w;
  }
  if (kh == 1)
    for (int b = 0; b < Bb; b++) part[b][c] = acc[b];
  __syncthreads();
  if (kh == 0)
    for (int b = 0; b < Bb; b++)
      gW[(size_t)b * 2048 + col] = acc[b] + part[b][c] + bc[col];
}

// ---------------------- level-0 leaf log-softmax ----------------------------
__global__ void k_leaf0(const float* __restrict__ hidd, const float* __restrict__ Wl,
                        const float* __restrict__ bl, float* __restrict__ leaves) {
  int b = threadIdx.x >> 6, lane = threadIdx.x & 63;
  float d0 = 0.f, d1 = 0.f;
  for (int k = lane; k < Hd; k += 64) {
    float h = hidd[(size_t)b * Hd + k];
    d0 += h * Wl[2 * k];
    d1 += h * Wl[2 * k + 1];
  }
  for (int off = 32; off; off >>= 1) {
    d0 += __shfl_down(d0, off);
    d1 += __shfl_down(d1, off);
  }
  if (lane == 0) {
    float l0 = d0 + bl[0], l1 = d1 + bl[1];
    float m = fmaxf(l0, l1);
    float L = logf(expf(l0 - m) + expf(l1 - m));
    leaves[b * 2 + 0] = l0 - m - L;
    leaves[b * 2 + 1] = l1 - m - L;
  }
}

// -------- tree cell GEMM: z[m][0:2048] = h[parent rows] @ Wc[:1024,:] -------
// bf16 MFMA, m97 structure; K split 4-way over blockIdx.z for parallelism on
// small levels; partials land in zbuf[ks][256][2048], summed in k_ln2.
__global__ __launch_bounds__(256) void k_cellg(
    const unsigned short* __restrict__ A, const unsigned short* __restrict__ Bt,
    float* __restrict__ zbuf, PR pr, int Mtot) {
  __shared__ short As[128 * 64];
  __shared__ short Bs[128 * 64];
  int tid = threadIdx.x;
  int lane = tid & 63, w = tid >> 6;
  int wm = w & 1, wn = w >> 1;
  int R0 = blockIdx.x * 128, C0 = blockIdx.y * 128;
  int ks = blockIdx.z;
  f32x4 acc[4][4];
#pragma unroll
  for (int i = 0; i < 4; i++)
#pragma unroll
    for (int j = 0; j < 4; j++) acc[i][j] = 0.f;
  int quad = lane >> 4, l15 = lane & 15;
  int srow = lane >> 3;
  int kc = lane & 7;
  for (int kb = ks * 4; kb < ks * 4 + 4; kb++) {
    int k0 = kb * 64;
#pragma unroll
    for (int i = 0; i < 4; i++) {
      int rowb = w * 32 + i * 8;
      int m = rowb + srow;
      int kcx = kc ^ (m & 7);
      int gr = R0 + m;
      int grc = gr < Mtot ? gr : 0;
      int arow = pr.v[grc >> 3] * Bb + (grc & 7);
      const unsigned short* ga = A + (size_t)arow * Hd + k0 + kcx * 8;
      const unsigned short* gb = Bt + (size_t)(C0 + m) * Hd + k0 + kcx * 8;
      __builtin_amdgcn_global_load_lds(
          (__attribute__((address_space(1))) void*)ga,
          (__attribute__((address_space(3))) void*)&As[rowb * 64], 16, 0, 0);
      __builtin_amdgcn_global_load_lds(
          (__attribute__((address_space(1))) void*)gb,
          (__attribute__((address_space(3))) void*)&Bs[rowb * 64], 16, 0, 0);
    }
    __syncthreads();
#pragma unroll
    for (int ksi = 0; ksi < 2; ksi++) {
      bf16x8 af[4], bfr[4];
      int kidx = ksi * 4 + quad;
#pragma unroll
      for (int i = 0; i < 4; i++) {
        int m = wm * 64 + i * 16 + l15;
        af[i] = *(const bf16x8*)&As[m * 64 + (kidx ^ (m & 7)) * 8];
      }
#pragma unroll
      for (int j = 0; j < 4; j++) {
        int n = wn * 64 + j * 16 + l15;
        bfr[j] = *(const bf16x8*)&Bs[n * 64 + (kidx ^ (n & 7)) * 8];
      }
#pragma unroll
      for (int i = 0; i < 4; i++)
#pragma unroll
        for (int j = 0; j < 4; j++)
          acc[i][j] = __builtin_amdgcn_mfma_f32_16x16x32_bf16(af[i], bfr[j],
                                                              acc[i][j], 0, 0, 0);
    }
    __syncthreads();
  }
#pragma unroll
  for (int j = 0; j < 4; j++) {
    int col = C0 + wn * 64 + j * 16 + l15;
#pragma unroll
    for (int i = 0; i < 4; i++) {
      int rowb = R0 + wm * 64 + i * 16 + quad * 4;
#pragma unroll
      for (int r = 0; r < 4; r++) {
        int row = rowb + r;
        if (row < Mtot)
          zbuf[((size_t)ks * 256 + row) * 2048 + col] = acc[i][j][r];
      }
    }
  }
}

// ---------- tree LN+tanh+leaf: one block per (child node, batch) ------------
// Shuffle-based reductions (2 barriers total); sums the 4 K-split partials.
__global__ void k_ln2(const float* __restrict__ zbuf, const float* __restrict__ gW,
                      const float* __restrict__ lng, const float* __restrict__ lnb,
                      const float* __restrict__ Wl, const float* __restrict__ bl,
                      unsigned short* __restrict__ hiddb,
                      float* __restrict__ leaves, PR pr, int lvlOff) {
  __shared__ float a1[4], a2[4], c1[4], c2[4];
  int tid = threadIdx.x, lane = tid & 63, wid = tid >> 6;
  int node = blockIdx.x, b = blockIdx.y;
  int cg = node & 1, p = node >> 1;
  int gp = pr.v[p];
  int ch = lvlOff + node;
  int m = p * Bb + b;
  int j0 = tid * 4;
  size_t zb = (size_t)m * 2048 + cg * 1024 + j0;
  f4 z = *(const f4*)&zbuf[zb];
  z += *(const f4*)&zbuf[zb + (size_t)256 * 2048];
  z += *(const f4*)&zbuf[zb + (size_t)512 * 2048];
  z += *(const f4*)&zbuf[zb + (size_t)768 * 2048];
  z += *(const f4*)&gW[(size_t)b * 2048 + cg * 1024 + j0];
  float s = z.x + z.y + z.z + z.w;
  float s2 = z.x * z.x + z.y * z.y + z.z * z.z + z.w * z.w;
#pragma unroll
  for (int off = 32; off; off >>= 1) {
    s += __shfl_xor(s, off);
    s2 += __shfl_xor(s2, off);
  }
  if (lane == 0) { a1[wid] = s; a2[wid] = s2; }
  __syncthreads();
  s = a1[0] + a1[1] + a1[2] + a1[3];
  s2 = a2[0] + a2[1] + a2[2] + a2[3];
  float mu = s * (1.f / 1024.f);
  float var = s2 * (1.f / 1024.f) - mu * mu;
  float rs = rsqrtf(var + 1e-5f);
  f4 lgv = *(const f4*)&lng[j0];
  f4 lbv = *(const f4*)&lnb[j0];
  f4 y;
  y.x = tanhf((z.x - mu) * rs * lgv.x + lbv.x);
  y.y = tanhf((z.y - mu) * rs * lgv.y + lbv.y);
  y.z = tanhf((z.z - mu) * rs * lgv.z + lbv.z);
  y.w = tanhf((z.w - mu) * rs * lgv.w + lbv.w);
  us4 yb;
  yb.x = f2bf(y.x); yb.y = f2bf(y.y); yb.z = f2bf(y.z); yb.w = f2bf(y.w);
  *(us4*)&hiddb[((size_t)ch * Bb + b) * Hd + j0] = yb;
  f4 wA = *(const f4*)&Wl[j0 * 2];
  f4 wB = *(const f4*)&Wl[j0 * 2 + 4];
  float d0 = y.x * wA.x + y.y * wA.z + y.z * wB.x + y.w * wB.z;
  float d1 = y.x * wA.y + y.y * wA.w + y.z * wB.y + y.w * wB.w;
#pragma unroll
  for (int off = 32; off; off >>= 1) {
    d0 += __shfl_xor(d0, off);
    d1 += __shfl_xor(d1, off);
  }
  if (lane == 0) { c1[wid] = d0; c2[wid] = d1; }
  __syncthreads();
  if (tid == 0) {
    float l0 = c1[0] + c1[1] + c1[2] + c1[3] + bl[0];
    float l1 = c2[0] + c2[1] + c2[2] + c2[3] + bl[1];
    float mm = fmaxf(l0, l1);
    float L = logf(expf(l0 - mm) + expf(l1 - mm));
    float half = 0.5f * leaves[((size_t)gp * Bb + b) * 2 + 1];
    leaves[((size_t)ch * Bb + b) * 2 + 0] = half + l0 - mm - L;
    leaves[((size_t)ch * Bb + b) * 2 + 1] = half + l1 - mm - L;
  }
}

// ----------------- big bf16 MFMA GEMM + fused softmax partials --------------
__global__ __launch_bounds__(256) void k_gemm(
    const unsigned short* __restrict__ A, const unsigned short* __restrict__ Bt,
    const float* __restrict__ bout, float* __restrict__ out,
    float2* __restrict__ ptile, int Mvalid) {
  __shared__ short As[128 * 64];
  __shared__ short Bs[128 * 64];
  int tid = threadIdx.x;
  int lane = tid & 63, w = tid >> 6;
  int wm = w & 1, wn = w >> 1;
  int R0 = blockIdx.x * 128, C0 = blockIdx.y * 128;
  f32x4 acc[4][4];
#pragma unroll
  for (int i = 0; i < 4; i++)
#pragma unroll
    for (int j = 0; j < 4; j++) acc[i][j] = 0.f;
  int quad = lane >> 4, l15 = lane & 15;
  int srow = lane >> 3;
  int kc = lane & 7;
  for (int kb = 0; kb < 16; kb++) {
    int k0 = kb * 64;
#pragma unroll
    for (int i = 0; i < 4; i++) {
      int rowb = w * 32 + i * 8;
      int m = rowb + srow;
      int kcx = kc ^ (m & 7);
      const unsigned short* ga = A + (size_t)(R0 + m) * Hd + k0 + kcx * 8;
      const unsigned short* gb = Bt + (size_t)(C0 + m) * Hd + k0 + kcx * 8;
      __builtin_amdgcn_global_load_lds(
          (__attribute__((address_space(1))) void*)ga,
          (__attribute__((address_space(3))) void*)&As[rowb * 64], 16, 0, 0);
      __builtin_amdgcn_global_load_lds(
          (__attribute__((address_space(1))) void*)gb,
          (__attribute__((address_space(3))) void*)&Bs[rowb * 64], 16, 0, 0);
    }
    __syncthreads();
#pragma unroll
    for (int ksi = 0; ksi < 2; ksi++) {
      bf16x8 af[4], bfr[4];
      int kidx = ksi * 4 + quad;
#pragma unroll
      for (int i = 0; i < 4; i++) {
        int m = wm * 64 + i * 16 + l15;
        af[i] = *(const bf16x8*)&As[m * 64 + (kidx ^ (m & 7)) * 8];
      }
#pragma unroll
      for (int j = 0; j < 4; j++) {
        int n = wn * 64 + j * 16 + l15;
        bfr[j] = *(const bf16x8*)&Bs[n * 64 + (kidx ^ (n & 7)) * 8];
      }
#pragma unroll
      for (int i = 0; i < 4; i++)
#pragma unroll
        for (int j = 0; j < 4; j++)
          acc[i][j] = __builtin_amdgcn_mfma_f32_16x16x32_bf16(af[i], bfr[j],
                                                              acc[i][j], 0, 0, 0);
    }
    __syncthreads();
  }
  // Epilogue: bias, nt-store, per-row (max, sumexp) partial over this block's
  // 128 cols. C/D layout: col = lane&15, row = quad*4 + reg [m89].
  // Max-first reduce: 4 shfl-max, then 4 native exp2, then 4 shfl-add.
  float2* sred = (float2*)As;  // safe: trailing sync above
  float bo[4];
#pragma unroll
  for (int j = 0; j < 4; j++) bo[j] = bout[C0 + wn * 64 + j * 16 + l15];
#pragma unroll
  for (int i = 0; i < 4; i++) {
#pragma unroll
    for (int r = 0; r < 4; r++) {
      int lr = wm * 64 + i * 16 + quad * 4 + r;
      int row = R0 + lr;
      float v0 = acc[i][0][r] + bo[0];
      float v1 = acc[i][1][r] + bo[1];
      float v2 = acc[i][2][r] + bo[2];
      float v3 = acc[i][3][r] + bo[3];
      if (row < Mvalid) {
        size_t base = (size_t)row * Vv + C0 + wn * 64 + l15;
        __builtin_nontemporal_store(v0, &out[base + 0]);
        __builtin_nontemporal_store(v1, &out[base + 16]);
        __builtin_nontemporal_store(v2, &out[base + 32]);
        __builtin_nontemporal_store(v3, &out[base + 48]);
      }
      float mx = fmaxf(fmaxf(v0, v1), fmaxf(v2, v3));
#pragma unroll
      for (int d = 1; d < 16; d <<= 1) mx = fmaxf(mx, __shfl_xor(mx, d));
      float sm = exp2f((v0 - mx) * L2E) + exp2f((v1 - mx) * L2E) +
                 exp2f((v2 - mx) * L2E) + exp2f((v3 - mx) * L2E);
#pragma unroll
      for (int d = 1; d < 16; d <<= 1) sm += __shfl_xor(sm, d);
      if (l15 == 0) { sred[wn * 128 + lr].x = mx; sred[wn * 128 + lr].y = sm; }
    }
  }
  __syncthreads();
  if (tid < 128) {
    float2 a = sred[tid], c = sred[128 + tid];
    float M = fmaxf(a.x, c.x);
    float S = a.y * exp2f((a.x - M) * L2E) + c.y * exp2f((c.x - M) * L2E);
    float2 o; o.x = M; o.y = S;
    ptile[(size_t)(R0 + tid) * NT + blockIdx.y] = o;
  }
}

// --------------------- reduce partial stats -> row LSE ----------------------
__global__ void k_lse(const float2* __restrict__ ptile, float* __restrict__ st) {
  __shared__ float ms[256], ss[256];
  int r = blockIdx.x, tid = threadIdx.x;
  float mx = -3e38f, sm = 0.f;
  for (int t = tid; t < NT; t += 256) {
    float2 e = ptile[(size_t)r * NT + t];
    float M = fmaxf(mx, e.x);
    sm = sm * exp2f((mx - M) * L2E) + e.y * exp2f((e.x - M) * L2E);
    mx = M;
  }
  ms[tid] = mx; ss[tid] = sm;
  __syncthreads();
  for (int o = 128; o; o >>= 1) {
    if (tid < o) {
      float m2 = ms[tid + o], s2 = ss[tid + o];
      float M = fmaxf(ms[tid], m2);
      ss[tid] = ss[tid] * exp2f((ms[tid] - M) * L2E) + s2 * exp2f((m2 - M) * L2E);
      ms[tid] = M;
    }
    __syncthreads();
  }
  if (tid == 0) st[r] = ms[0] + logf(ss[0]);
}

// --------------------------- normalize in place -----------------------------
__global__ void k_norm(float* __restrict__ out, const float* __restrict__ st) {
  int r = blockIdx.y;
  int i = blockIdx.x * 256 + threadIdx.x;
  if (i < Vv / 4) {
    float sub = st[r];
    f4* p = (f4*)(out + (size_t)r * Vv) + i;
    f4 v = __builtin_nontemporal_load(p);
    v -= sub;
    __builtin_nontemporal_store(v, p);
  }
}

// ------------------------- static index outputs -----------------------------
__global__ void k_idx(float* __restrict__ dst) {
  int total = DS.nStart + DS.nEnd + 2 * DS.nS;
  for (int i = threadIdx.x; i < total; i += 256) {
    int v;
    if (i < DS.nStart) v = DS.startIdx[i];
    else if (i < DS.nStart + DS.nEnd) v = DS.endIdx[i - DS.nStart];
    else if (i < DS.nStart + DS.nEnd + DS.nS) v = DS.sOut[i - DS.nStart - DS.nEnd];
    else v = DS.sIn[i - DS.nStart - DS.nEnd - DS.nS];
    dst[i] = (float)v;
  }
}

// ---------------------------------------------------------------------------
extern "C" void kernel_launch(void* const* d_in, const int* in_sizes, int n_in,
                              void* d_out, int out_size, void* d_ws, size_t ws_size,
                              hipStream_t stream) {
  (void)in_sizes; (void)n_in; (void)out_size; (void)ws_size;
  const float* x    = (const float*)d_in[0];
  const float* Win  = (const float*)d_in[1];
  const float* bin  = (const float*)d_in[2];
  const float* Wg   = (const float*)d_in[3];
  const float* bg   = (const float*)d_in[4];
  const float* Wc   = (const float*)d_in[5];
  const float* bc   = (const float*)d_in[6];
  const float* lng  = (const float*)d_in[7];
  const float* lnb  = (const float*)d_in[8];
  const float* Wl   = (const float*)d_in[9];
  const float* bl   = (const float*)d_in[10];
  const float* Wout = (const float*)d_in[11];
  const float* bout = (const float*)d_in[12];
  float* out = (float*)d_out;

  constexpr int T = HS.T;                          // 351
  constexpr int Mrows = T * Bb;                    // 2808
  constexpr int Mt = ((Mrows + 127) / 128) * 128;  // 2816

  char* ws = (char*)d_ws;
  unsigned short* Wt = (unsigned short*)ws;    ws += (size_t)Vv * Hd * 2;
  unsigned short* Wct = (unsigned short*)ws;   ws += (size_t)2048 * Hd * 2;
  float* hidd = (float*)ws;                    ws += (size_t)Bb * Hd * 4;   // leaf0 only
  unsigned short* hiddb = (unsigned short*)ws; ws += (size_t)Mt * Hd * 2;
  float* gbuf = (float*)ws;                    ws += (size_t)Bb * Hd * 4;
  float* gW = (float*)ws;                      ws += (size_t)Bb * 2048 * 4;
  float* zbuf = (float*)ws;                    ws += (size_t)4 * 256 * 2048 * 4;
  float2* ptile = (float2*)ws;                 ws += (size_t)Mt * NT * 8;
  float* st = (float*)ws;                      ws += (size_t)Mt * 4;

  float* leaves = out + (size_t)Mrows * Vv;
  float* idxdst = leaves + (size_t)Mrows * 2;

  k_wout_t<<<dim3(Vv / 128, Hd / 64), dim3(256), 0, stream>>>(Wout, Wt);
  k_wct<<<dim3(2048 / 32, Hd / 32), dim3(32, 8), 0, stream>>>(Wc, Wct);
  k_init<<<dim3(8, 2), dim3(256), 0, stream>>>(x, Wg, bg, Win, bin, gbuf, hidd, hiddb);
  k_gw<<<dim3(16), dim3(256), 0, stream>>>(gbuf, Wc, bc, gW);
  k_leaf0<<<dim3(1), dim3(512), 0, stream>>>(hidd, Wl, bl, leaves);

  for (int l = 1; l < DEPTH; l++) {
    int Pc = HS.parCnt[l - 1];
    int Mtot = Pc * Bb;
    int Mtiles = (Mtot + 127) / 128;
    PR pr{};
    for (int i = 0; i < Pc; i++) pr.v[i] = HS.parRows[l - 1][i];
    k_cellg<<<dim3(Mtiles, 16, 4), dim3(256), 0, stream>>>(hiddb, Wct, zbuf, pr, Mtot);
    k_ln2<<<dim3(2 * Pc, Bb), dim3(256), 0, stream>>>(zbuf, gW, lng, lnb, Wl, bl,
                                                      hiddb, leaves, pr,
                                                      HS.lvlOff[l]);
  }

  k_gemm<<<dim3(Mt / 128, Vv / 128), dim3(256), 0, stream>>>(hiddb, Wt, bout, out,
                                                             ptile, Mrows);
  k_lse<<<dim3(Mrows), dim3(256), 0, stream>>>(ptile, st);
  k_norm<<<dim3(32, Mrows), dim3(256), 0, stream>>>(out, st);
  k_idx<<<dim3(1), dim3(256), 0, stream>>>(idxdst);
}

// Round 3
// 1117.703 us; speedup vs baseline: 1.2541x; 1.0152x over previous
//
#include <hip/hip_runtime.h>
#include <cstdint>
#include <cstddef>

// ---------------------------------------------------------------------------
// OrderedMemoryDecoder (DEPTH=14, B=8, H=1024, V=32000) for gfx950.
// R4: k_gemm XCD-aware column-chunk swizzle (B-panel L2 reuse);
// epilogue shuffle-butterflies -> LDS scoreboard reduce;
// optional bf16 logit staging (gated on ws_size) to halve the out-stream.
// ---------------------------------------------------------------------------

typedef __attribute__((ext_vector_type(4))) float   f4;
typedef __attribute__((ext_vector_type(4))) float   f32x4;
typedef __attribute__((ext_vector_type(8))) __bf16  bf16x8;
typedef __attribute__((ext_vector_type(4))) unsigned short us4;
typedef __attribute__((ext_vector_type(8))) unsigned short us8;

constexpr int DEPTH = 14;
constexpr int Bb = 8;
constexpr int Hd = 1024;
constexpr int Vv = 32000;
constexpr int NT = Vv / 128;   // 250 N-tiles in big GEMM
constexpr int MAXT = 512;
constexpr int MAXS = 4096;
constexpr int MAXP = 32;
constexpr float L2E = 1.44269504088896340736f;

struct SB {
  int lvlOff[DEPTH + 1];
  int lvlK[DEPTH];
  int len[MAXT];
  int lch[MAXT], rch[MAXT];
  int parCnt[DEPTH];
  int parRows[DEPTH][MAXP];
  int T;
  int nS;
  int sOut[MAXS], sIn[MAXS];
  int nStart, nEnd;
  int startIdx[16], endIdx[16];
};

constexpr int ceil75(int L) {
  constexpr int t[14] = {0, 1, 2, 3, 3, 4, 4, 5, 5, 6, 6, 7, 7, 7};
  return t[L];
}

constexpr SB build() {
  SB s{};
  for (int i = 0; i < MAXT; i++) { s.lch[i] = -1; s.rch[i] = -1; }
  s.lvlOff[0] = 0; s.lvlK[0] = 1; s.len[0] = DEPTH;
  for (int l = 0; l < DEPTH - 1; l++) {
    int off = s.lvlOff[l], K = s.lvlK[l];
    int nxt = off + K, cnt = 0;
    for (int i = 0; i < K; i++) {
      int g = off + i;
      if (s.len[g] > 1) {
        int gl = nxt + 2 * cnt, gr = gl + 1;
        s.lch[g] = gl; s.rch[g] = gr;
        s.len[gl] = ceil75(s.len[g] - 1);
        s.len[gr] = s.len[g] - 1;
        s.parRows[l][cnt] = g;
        cnt++;
      }
    }
    s.parCnt[l] = cnt;
    s.lvlOff[l + 1] = nxt;
    s.lvlK[l + 1] = 2 * cnt;
  }
  s.T = s.lvlOff[DEPTH - 1] + s.lvlK[DEPTH - 1];
  s.nS = 0;
  for (int l = DEPTH - 2; l >= 0; l--) {
    for (int pi = 0; pi < s.parCnt[l]; pi++) {
      int g = s.parRows[l][pi];
      for (int u = s.lch[g]; u != -1; u = s.rch[u])
        for (int v = s.rch[g]; v != -1; v = s.lch[v]) {
          s.sOut[s.nS] = u; s.sIn[s.nS] = v; s.nS++;
        }
    }
  }
  s.nStart = 0;
  for (int u = 0; u != -1; u = s.lch[u]) s.startIdx[s.nStart++] = u;
  s.nEnd = 0;
  for (int u = 0; u != -1; u = s.rch[u]) s.endIdx[s.nEnd++] = u;
  return s;
}

constexpr SB HS = build();
__device__ const SB DS = build();

struct PR { int v[MAXP]; };

__device__ __forceinline__ unsigned short f2bf(float f) {
  union { float f; unsigned u; } v; v.f = f;
  unsigned r = v.u + 0x7fffu + ((v.u >> 16) & 1u);  // RNE
  return (unsigned short)(r >> 16);
}

// --------------------------- W_out -> bf16, transposed ----------------------
__global__ void k_wout_t(const float* __restrict__ Wout,
                         unsigned short* __restrict__ Wt) {
  __shared__ float t[64][129];
  int tid = threadIdx.x;
  int n0 = blockIdx.x * 128, k0 = blockIdx.y * 64;
#pragma unroll
  for (int i = 0; i < 8; i++) {
    int k = (tid >> 5) + 8 * i;
    int c = (tid & 31) * 4;
    f4 v = *(const f4*)&Wout[(size_t)(k0 + k) * Vv + n0 + c];
    t[k][c] = v.x; t[k][c + 1] = v.y; t[k][c + 2] = v.z; t[k][c + 3] = v.w;
  }
  __syncthreads();
#pragma unroll
  for (int pass = 0; pass < 4; pass++) {
    int n = (tid >> 3) + 32 * pass;
    int ks = (tid & 7) * 8;
    us8 o;
#pragma unroll
    for (int q = 0; q < 8; q++) o[q] = f2bf(t[ks + q][n]);
    *(us8*)&Wt[(size_t)(n0 + n) * Hd + k0 + ks] = o;
  }
}

// --------------- W_cell[:1024,:] -> bf16, transposed [2048][1024] -----------
__global__ void k_wct(const float* __restrict__ Wc,
                      unsigned short* __restrict__ Wct) {
  __shared__ float t[32][33];
  int tx = threadIdx.x, ty = threadIdx.y;
  int n0 = blockIdx.x * 32, k0 = blockIdx.y * 32;
  for (int i = 0; i < 4; i++)
    t[ty + 8 * i][tx] = Wc[(size_t)(k0 + ty + 8 * i) * 2048 + n0 + tx];
  __syncthreads();
  for (int i = 0; i < 4; i++)
    Wct[(size_t)(n0 + ty + 8 * i) * Hd + k0 + tx] = f2bf(t[tx][ty + 8 * i]);
}

// ------------------------------ g and h0 ------------------------------------
__global__ void k_init(const float* __restrict__ x, const float* __restrict__ Wg,
                       const float* __restrict__ bg, const float* __restrict__ Win,
                       const float* __restrict__ bin, float* __restrict__ gbuf,
                       float* __restrict__ hidd, unsigned short* __restrict__ hiddb) {
  __shared__ float xs[Bb * Hd];
  __shared__ float part[Bb][128];
  int tid = threadIdx.x;
  int mat = blockIdx.y;
  const float* W = mat ? Win : Wg;
  const float* bias = mat ? bin : bg;
  for (int i = tid; i < Bb * Hd; i += 256) xs[i] = x[i];
  __syncthreads();
  int c = tid & 127, kh = tid >> 7;
  int col = blockIdx.x * 128 + c;
  float acc[Bb];
#pragma unroll
  for (int b = 0; b < Bb; b++) acc[b] = 0.f;
  for (int k = kh * 512; k < kh * 512 + 512; k++) {
    float w = W[(size_t)k * Hd + col];
#pragma unroll
    for (int b = 0; b < Bb; b++) acc[b] += xs[b * Hd + k] * w;
  }
  if (kh == 1)
    for (int b = 0; b < Bb; b++) part[b][c] = acc[b];
  __syncthreads();
  if (kh == 0) {
    for (int b = 0; b < Bb; b++) {
      float v = acc[b] + part[b][c] + bias[col];
      if (mat == 0) gbuf[b * Hd + col] = v;
      else { hidd[(size_t)b * Hd + col] = v; hiddb[(size_t)b * Hd + col] = f2bf(v); }
    }
  }
}

// --------------------- gW = g @ W_cell[1024:,:] + b_cell --------------------
__global__ void k_gw(const float* __restrict__ gbuf, const float* __restrict__ Wc,
                     const float* __restrict__ bc, float* __restrict__ gW) {
  __shared__ float xs[Bb * Hd];
  __shared__ float part[Bb][128];
  int tid = threadIdx.x;
  for (int i = tid; i < Bb * Hd; i += 256) xs[i] = gbuf[i];
  __syncthreads();
  int c = tid & 127, kh = tid >> 7;
  int col = blockIdx.x * 128 + c;
  float acc[Bb];
#pragma unroll
  for (int b = 0; b < Bb; b++) acc[b] = 0.f;
  for (int k = kh * 512; k < kh * 512 + 512; k++) {
    float w = Wc[(size_t)(Hd + k) * 2048 + col];
#pragma unroll
    for (int b = 0; b < Bb; b++) acc[b] += xs[b * Hd + k] * w;
  }
  if (kh == 1)
    for (int b = 0; b < Bb; b++) part[b][c] = acc[b];
  __syncthreads();
  if (kh == 0)
    for (int b = 0; b < Bb; b++)
      gW[(size_t)b * 2048 + col] = acc[b] + part[b][c] + bc[col];
}

// ---------------------- level-0 leaf log-softmax ----------------------------
__global__ void k_leaf0(const float* __restrict__ hidd, const float* __restrict__ Wl,
                        const float* __restrict__ bl, float* __restrict__ leaves) {
  int b = threadIdx.x >> 6, lane = threadIdx.x & 63;
  float d0 = 0.f, d1 = 0.f;
  for (int k = lane; k < Hd; k += 64) {
    float h = hidd[(size_t)b * Hd + k];
    d0 += h * Wl[2 * k];
    d1 += h * Wl[2 * k + 1];
  }
  for (int off = 32; off; off >>= 1) {
    d0 += __shfl_down(d0, off);
    d1 += __shfl_down(d1, off);
  }
  if (lane == 0) {
    float l0 = d0 + bl[0], l1 = d1 + bl[1];
    float m = fmaxf(l0, l1);
    float L = logf(expf(l0 - m) + expf(l1 - m));
    leaves[b * 2 + 0] = l0 - m - L;
    leaves[b * 2 + 1] = l1 - m - L;
  }
}

// -------- tree cell GEMM: z[m][0:2048] = h[parent rows] @ Wc[:1024,:] -------
__global__ __launch_bounds__(256) void k_cellg(
    const unsigned short* __restrict__ A, const unsigned short* __restrict__ Bt,
    float* __restrict__ zbuf, PR pr, int Mtot) {
  __shared__ short As[128 * 64];
  __shared__ short Bs[128 * 64];
  int tid = threadIdx.x;
  int lane = tid & 63, w = tid >> 6;
  int wm = w & 1, wn = w >> 1;
  int R0 = blockIdx.x * 128, C0 = blockIdx.y * 128;
  int ks = blockIdx.z;
  f32x4 acc[4][4];
#pragma unroll
  for (int i = 0; i < 4; i++)
#pragma unroll
    for (int j = 0; j < 4; j++) acc[i][j] = 0.f;
  int quad = lane >> 4, l15 = lane & 15;
  int srow = lane >> 3;
  int kc = lane & 7;
  for (int kb = ks * 4; kb < ks * 4 + 4; kb++) {
    int k0 = kb * 64;
#pragma unroll
    for (int i = 0; i < 4; i++) {
      int rowb = w * 32 + i * 8;
      int m = rowb + srow;
      int kcx = kc ^ (m & 7);
      int gr = R0 + m;
      int grc = gr < Mtot ? gr : 0;
      int arow = pr.v[grc >> 3] * Bb + (grc & 7);
      const unsigned short* ga = A + (size_t)arow * Hd + k0 + kcx * 8;
      const unsigned short* gb = Bt + (size_t)(C0 + m) * Hd + k0 + kcx * 8;
      __builtin_amdgcn_global_load_lds(
          (__attribute__((address_space(1))) void*)ga,
          (__attribute__((address_space(3))) void*)&As[rowb * 64], 16, 0, 0);
      __builtin_amdgcn_global_load_lds(
          (__attribute__((address_space(1))) void*)gb,
          (__attribute__((address_space(3))) void*)&Bs[rowb * 64], 16, 0, 0);
    }
    __syncthreads();
#pragma unroll
    for (int ksi = 0; ksi < 2; ksi++) {
      bf16x8 af[4], bfr[4];
      int kidx = ksi * 4 + quad;
#pragma unroll
      for (int i = 0; i < 4; i++) {
        int m = wm * 64 + i * 16 + l15;
        af[i] = *(const bf16x8*)&As[m * 64 + (kidx ^ (m & 7)) * 8];
      }
#pragma unroll
      for (int j = 0; j < 4; j++) {
        int n = wn * 64 + j * 16 + l15;
        bfr[j] = *(const bf16x8*)&Bs[n * 64 + (kidx ^ (n & 7)) * 8];
      }
#pragma unroll
      for (int i = 0; i < 4; i++)
#pragma unroll
        for (int j = 0; j < 4; j++)
          acc[i][j] = __builtin_amdgcn_mfma_f32_16x16x32_bf16(af[i], bfr[j],
                                                              acc[i][j], 0, 0, 0);
    }
    __syncthreads();
  }
#pragma unroll
  for (int j = 0; j < 4; j++) {
    int col = C0 + wn * 64 + j * 16 + l15;
#pragma unroll
    for (int i = 0; i < 4; i++) {
      int rowb = R0 + wm * 64 + i * 16 + quad * 4;
#pragma unroll
      for (int r = 0; r < 4; r++) {
        int row = rowb + r;
        if (row < Mtot)
          zbuf[((size_t)ks * 256 + row) * 2048 + col] = acc[i][j][r];
      }
    }
  }
}

// ---------- tree LN+tanh+leaf: one block per (child node, batch) ------------
__global__ void k_ln2(const float* __restrict__ zbuf, const float* __restrict__ gW,
                      const float* __restrict__ lng, const float* __restrict__ lnb,
                      const float* __restrict__ Wl, const float* __restrict__ bl,
                      unsigned short* __restrict__ hiddb,
                      float* __restrict__ leaves, PR pr, int lvlOff) {
  __shared__ float a1[4], a2[4], c1[4], c2[4];
  int tid = threadIdx.x, lane = tid & 63, wid = tid >> 6;
  int node = blockIdx.x, b = blockIdx.y;
  int cg = node & 1, p = node >> 1;
  int gp = pr.v[p];
  int ch = lvlOff + node;
  int m = p * Bb + b;
  int j0 = tid * 4;
  size_t zb = (size_t)m * 2048 + cg * 1024 + j0;
  f4 z = *(const f4*)&zbuf[zb];
  z += *(const f4*)&zbuf[zb + (size_t)256 * 2048];
  z += *(const f4*)&zbuf[zb + (size_t)512 * 2048];
  z += *(const f4*)&zbuf[zb + (size_t)768 * 2048];
  z += *(const f4*)&gW[(size_t)b * 2048 + cg * 1024 + j0];
  float s = z.x + z.y + z.z + z.w;
  float s2 = z.x * z.x + z.y * z.y + z.z * z.z + z.w * z.w;
#pragma unroll
  for (int off = 32; off; off >>= 1) {
    s += __shfl_xor(s, off);
    s2 += __shfl_xor(s2, off);
  }
  if (lane == 0) { a1[wid] = s; a2[wid] = s2; }
  __syncthreads();
  s = a1[0] + a1[1] + a1[2] + a1[3];
  s2 = a2[0] + a2[1] + a2[2] + a2[3];
  float mu = s * (1.f / 1024.f);
  float var = s2 * (1.f / 1024.f) - mu * mu;
  float rs = rsqrtf(var + 1e-5f);
  f4 lgv = *(const f4*)&lng[j0];
  f4 lbv = *(const f4*)&lnb[j0];
  f4 y;
  y.x = tanhf((z.x - mu) * rs * lgv.x + lbv.x);
  y.y = tanhf((z.y - mu) * rs * lgv.y + lbv.y);
  y.z = tanhf((z.z - mu) * rs * lgv.z + lbv.z);
  y.w = tanhf((z.w - mu) * rs * lgv.w + lbv.w);
  us4 yb;
  yb.x = f2bf(y.x); yb.y = f2bf(y.y); yb.z = f2bf(y.z); yb.w = f2bf(y.w);
  *(us4*)&hiddb[((size_t)ch * Bb + b) * Hd + j0] = yb;
  f4 wA = *(const f4*)&Wl[j0 * 2];
  f4 wB = *(const f4*)&Wl[j0 * 2 + 4];
  float d0 = y.x * wA.x + y.y * wA.z + y.z * wB.x + y.w * wB.z;
  float d1 = y.x * wA.y + y.y * wA.w + y.z * wB.y + y.w * wB.w;
#pragma unroll
  for (int off = 32; off; off >>= 1) {
    d0 += __shfl_xor(d0, off);
    d1 += __shfl_xor(d1, off);
  }
  if (lane == 0) { c1[wid] = d0; c2[wid] = d1; }
  __syncthreads();
  if (tid == 0) {
    float l0 = c1[0] + c1[1] + c1[2] + c1[3] + bl[0];
    float l1 = c2[0] + c2[1] + c2[2] + c2[3] + bl[1];
    float mm = fmaxf(l0, l1);
    float L = logf(expf(l0 - mm) + expf(l1 - mm));
    float half = 0.5f * leaves[((size_t)gp * Bb + b) * 2 + 1];
    leaves[((size_t)ch * Bb + b) * 2 + 0] = half + l0 - mm - L;
    leaves[((size_t)ch * Bb + b) * 2 + 1] = half + l1 - mm - L;
  }
}

// ----------------- big bf16 MFMA GEMM + fused softmax partials --------------
// 1D grid with bijective XCD column-chunk swizzle: each XCD owns ~31
// consecutive N-columns; the 22 M-tiles of a column share its B-panel in
// that XCD's L2. BF=1: store logits bf16 to lgt; BF=0: fp32 to outf.
constexpr int MT_TILES = 22;           // Mt/128
constexpr int NWG = MT_TILES * NT;     // 5500

template <int BF>
__global__ __launch_bounds__(256) void k_gemm(
    const unsigned short* __restrict__ A, const unsigned short* __restrict__ Bt,
    const float* __restrict__ bout, float* __restrict__ outf,
    unsigned short* __restrict__ lgt, float2* __restrict__ ptile, int Mvalid) {
  __shared__ short As[128 * 64];
  __shared__ short Bs[128 * 64];
  int tid = threadIdx.x;
  int lane = tid & 63, w = tid >> 6;
  int wm = w & 1, wn = w >> 1;
  // bijective XCD swizzle (m204): xcd = bid&7 gets a contiguous wgid chunk
  int bid = blockIdx.x;
  constexpr int q = NWG >> 3, r = NWG & 7;
  int xcd = bid & 7, idx = bid >> 3;
  int wgid = (xcd < r ? xcd * (q + 1) : r * (q + 1) + (xcd - r) * q) + idx;
  int ny = wgid / MT_TILES;
  int mx = wgid - ny * MT_TILES;
  int R0 = mx * 128, C0 = ny * 128;
  f32x4 acc[4][4];
#pragma unroll
  for (int i = 0; i < 4; i++)
#pragma unroll
    for (int j = 0; j < 4; j++) acc[i][j] = 0.f;
  int quad = lane >> 4, l15 = lane & 15;
  int srow = lane >> 3;
  int kc = lane & 7;
  for (int kb = 0; kb < 16; kb++) {
    int k0 = kb * 64;
#pragma unroll
    for (int i = 0; i < 4; i++) {
      int rowb = w * 32 + i * 8;
      int m = rowb + srow;
      int kcx = kc ^ (m & 7);
      const unsigned short* ga = A + (size_t)(R0 + m) * Hd + k0 + kcx * 8;
      const unsigned short* gb = Bt + (size_t)(C0 + m) * Hd + k0 + kcx * 8;
      __builtin_amdgcn_global_load_lds(
          (__attribute__((address_space(1))) void*)ga,
          (__attribute__((address_space(3))) void*)&As[rowb * 64], 16, 0, 0);
      __builtin_amdgcn_global_load_lds(
          (__attribute__((address_space(1))) void*)gb,
          (__attribute__((address_space(3))) void*)&Bs[rowb * 64], 16, 0, 0);
    }
    __syncthreads();
#pragma unroll
    for (int ksi = 0; ksi < 2; ksi++) {
      bf16x8 af[4], bfr[4];
      int kidx = ksi * 4 + quad;
#pragma unroll
      for (int i = 0; i < 4; i++) {
        int m = wm * 64 + i * 16 + l15;
        af[i] = *(const bf16x8*)&As[m * 64 + (kidx ^ (m & 7)) * 8];
      }
#pragma unroll
      for (int j = 0; j < 4; j++) {
        int n = wn * 64 + j * 16 + l15;
        bfr[j] = *(const bf16x8*)&Bs[n * 64 + (kidx ^ (n & 7)) * 8];
      }
#pragma unroll
      for (int i = 0; i < 4; i++)
#pragma unroll
        for (int j = 0; j < 4; j++)
          acc[i][j] = __builtin_amdgcn_mfma_f32_16x16x32_bf16(af[i], bfr[j],
                                                              acc[i][j], 0, 0, 0);
    }
    __syncthreads();
  }
  // Epilogue: bias, store, per-row (max, sumexp) 4-col partials into an LDS
  // scoreboard (no cross-lane shuffles), then a 128-thread two-pass merge.
  // C/D layout: col = lane&15, row = quad*4 + reg [m89].
  float2* s0 = (float2*)As;            // wn=0 partials [128 rows][16 groups]
  float2* s1 = (float2*)Bs;            // wn=1 partials
  float2* sw = wn ? s1 : s0;
  float bo[4];
#pragma unroll
  for (int j = 0; j < 4; j++) bo[j] = bout[C0 + wn * 64 + j * 16 + l15];
#pragma unroll
  for (int i = 0; i < 4; i++) {
#pragma unroll
    for (int r2 = 0; r2 < 4; r2++) {
      int lr = wm * 64 + i * 16 + quad * 4 + r2;
      int row = R0 + lr;
      float v0 = acc[i][0][r2] + bo[0];
      float v1 = acc[i][1][r2] + bo[1];
      float v2 = acc[i][2][r2] + bo[2];
      float v3 = acc[i][3][r2] + bo[3];
      if (row < Mvalid) {
        size_t base = (size_t)row * Vv + C0 + wn * 64 + l15;
        if (BF) {
          __builtin_nontemporal_store(f2bf(v0), &lgt[base + 0]);
          __builtin_nontemporal_store(f2bf(v1), &lgt[base + 16]);
          __builtin_nontemporal_store(f2bf(v2), &lgt[base + 32]);
          __builtin_nontemporal_store(f2bf(v3), &lgt[base + 48]);
        } else {
          __builtin_nontemporal_store(v0, &outf[base + 0]);
          __builtin_nontemporal_store(v1, &outf[base + 16]);
          __builtin_nontemporal_store(v2, &outf[base + 32]);
          __builtin_nontemporal_store(v3, &outf[base + 48]);
        }
      }
      float mx4 = fmaxf(fmaxf(v0, v1), fmaxf(v2, v3));
      float sm4 = exp2f((v0 - mx4) * L2E) + exp2f((v1 - mx4) * L2E) +
                  exp2f((v2 - mx4) * L2E) + exp2f((v3 - mx4) * L2E);
      float2 e; e.x = mx4; e.y = sm4;
      sw[lr * 16 + l15] = e;
    }
  }
  __syncthreads();
  if (tid < 128) {
    int rot = tid & 15;
    float M = -3e38f;
#pragma unroll
    for (int t = 0; t < 16; t++) {
      int c = (t + rot) & 15;
      M = fmaxf(M, fmaxf(s0[tid * 16 + c].x, s1[tid * 16 + c].x));
    }
    float S = 0.f;
#pragma unroll
    for (int t = 0; t < 16; t++) {
      int c = (t + rot) & 15;
      float2 a = s0[tid * 16 + c], b = s1[tid * 16 + c];
      S += a.y * exp2f((a.x - M) * L2E) + b.y * exp2f((b.x - M) * L2E);
    }
    float2 o; o.x = M; o.y = S;
    ptile[(size_t)(R0 + tid) * NT + ny] = o;
  }
}

// --------------------- reduce partial stats -> row LSE ----------------------
__global__ void k_lse(const float2* __restrict__ ptile, float* __restrict__ st) {
  __shared__ float ms[256], ss[256];
  int r = blockIdx.x, tid = threadIdx.x;
  float mx = -3e38f, sm = 0.f;
  for (int t = tid; t < NT; t += 256) {
    float2 e = ptile[(size_t)r * NT + t];
    float M = fmaxf(mx, e.x);
    sm = sm * exp2f((mx - M) * L2E) + e.y * exp2f((e.x - M) * L2E);
    mx = M;
  }
  ms[tid] = mx; ss[tid] = sm;
  __syncthreads();
  for (int o = 128; o; o >>= 1) {
    if (tid < o) {
      float m2 = ms[tid + o], s2 = ss[tid + o];
      float M = fmaxf(ms[tid], m2);
      ss[tid] = ss[tid] * exp2f((ms[tid] - M) * L2E) + s2 * exp2f((m2 - M) * L2E);
      ms[tid] = M;
    }
    __syncthreads();
  }
  if (tid == 0) st[r] = ms[0] + logf(ss[0]);
}

// ------------------- normalize: fp32 in place (fallback) --------------------
__global__ void k_norm(float* __restrict__ out, const float* __restrict__ st) {
  int r = blockIdx.y;
  int i = blockIdx.x * 256 + threadIdx.x;
  if (i < Vv / 4) {
    float sub = st[r];
    f4* p = (f4*)(out + (size_t)r * Vv) + i;
    f4 v = __builtin_nontemporal_load(p);
    v -= sub;
    __builtin_nontemporal_store(v, p);
  }
}

// ------------------- normalize: bf16 logits -> fp32 out ---------------------
__global__ void k_norm_bf(const unsigned short* __restrict__ lgt,
                          float* __restrict__ out, const float* __restrict__ st) {
  int r = blockIdx.y;
  int i = blockIdx.x * 256 + threadIdx.x;
  if (i < Vv / 8) {
    float sub = st[r];
    us8 v = __builtin_nontemporal_load((const us8*)(lgt + (size_t)r * Vv + i * 8));
    f4 o0, o1;
#pragma unroll
    for (int qk = 0; qk < 4; qk++) {
      union { unsigned u; float f; } cv;
      cv.u = ((unsigned)v[qk]) << 16;
      o0[qk] = cv.f - sub;
    }
#pragma unroll
    for (int qk = 0; qk < 4; qk++) {
      union { unsigned u; float f; } cv;
      cv.u = ((unsigned)v[4 + qk]) << 16;
      o1[qk] = cv.f - sub;
    }
    float* p = out + (size_t)r * Vv + i * 8;
    __builtin_nontemporal_store(o0, (f4*)p);
    __builtin_nontemporal_store(o1, (f4*)(p + 4));
  }
}

// ------------------------- static index outputs -----------------------------
__global__ void k_idx(float* __restrict__ dst) {
  int total = DS.nStart + DS.nEnd + 2 * DS.nS;
  for (int i = threadIdx.x; i < total; i += 256) {
    int v;
    if (i < DS.nStart) v = DS.startIdx[i];
    else if (i < DS.nStart + DS.nEnd) v = DS.endIdx[i - DS.nStart];
    else if (i < DS.nStart + DS.nEnd + DS.nS) v = DS.sOut[i - DS.nStart - DS.nEnd];
    else v = DS.sIn[i - DS.nStart - DS.nEnd - DS.nS];
    dst[i] = (float)v;
  }
}

// ---------------------------------------------------------------------------
extern "C" void kernel_launch(void* const* d_in, const int* in_sizes, int n_in,
                              void* d_out, int out_size, void* d_ws, size_t ws_size,
                              hipStream_t stream) {
  (void)in_sizes; (void)n_in; (void)out_size;
  const float* x    = (const float*)d_in[0];
  const float* Win  = (const float*)d_in[1];
  const float* bin  = (const float*)d_in[2];
  const float* Wg   = (const float*)d_in[3];
  const float* bg   = (const float*)d_in[4];
  const float* Wc   = (const float*)d_in[5];
  const float* bc   = (const float*)d_in[6];
  const float* lng  = (const float*)d_in[7];
  const float* lnb  = (const float*)d_in[8];
  const float* Wl   = (const float*)d_in[9];
  const float* bl   = (const float*)d_in[10];
  const float* Wout = (const float*)d_in[11];
  const float* bout = (const float*)d_in[12];
  float* out = (float*)d_out;

  constexpr int T = HS.T;                          // 351
  constexpr int Mrows = T * Bb;                    // 2808
  constexpr int Mt = ((Mrows + 127) / 128) * 128;  // 2816

  char* ws = (char*)d_ws;
  char* ws0 = ws;
  unsigned short* Wt = (unsigned short*)ws;    ws += (size_t)Vv * Hd * 2;
  unsigned short* Wct = (unsigned short*)ws;   ws += (size_t)2048 * Hd * 2;
  float* hidd = (float*)ws;                    ws += (size_t)Bb * Hd * 4;   // leaf0 only
  unsigned short* hiddb = (unsigned short*)ws; ws += (size_t)Mt * Hd * 2;
  float* gbuf = (float*)ws;                    ws += (size_t)Bb * Hd * 4;
  float* gW = (float*)ws;                      ws += (size_t)Bb * 2048 * 4;
  float* zbuf = (float*)ws;                    ws += (size_t)4 * 256 * 2048 * 4;
  float2* ptile = (float2*)ws;                 ws += (size_t)Mt * NT * 8;
  float* st = (float*)ws;                      ws += (size_t)Mt * 4;
  unsigned short* lgt = (unsigned short*)ws;   // optional, gated on ws_size
  size_t needBf = (size_t)(ws - ws0) + (size_t)Mt * Vv * 2;
  bool bfp = ws_size >= needBf;

  float* leaves = out + (size_t)Mrows * Vv;
  float* idxdst = leaves + (size_t)Mrows * 2;

  k_wout_t<<<dim3(Vv / 128, Hd / 64), dim3(256), 0, stream>>>(Wout, Wt);
  k_wct<<<dim3(2048 / 32, Hd / 32), dim3(32, 8), 0, stream>>>(Wc, Wct);
  k_init<<<dim3(8, 2), dim3(256), 0, stream>>>(x, Wg, bg, Win, bin, gbuf, hidd, hiddb);
  k_gw<<<dim3(16), dim3(256), 0, stream>>>(gbuf, Wc, bc, gW);
  k_leaf0<<<dim3(1), dim3(512), 0, stream>>>(hidd, Wl, bl, leaves);

  for (int l = 1; l < DEPTH; l++) {
    int Pc = HS.parCnt[l - 1];
    int Mtot = Pc * Bb;
    int Mtiles = (Mtot + 127) / 128;
    PR pr{};
    for (int i = 0; i < Pc; i++) pr.v[i] = HS.parRows[l - 1][i];
    k_cellg<<<dim3(Mtiles, 16, 4), dim3(256), 0, stream>>>(hiddb, Wct, zbuf, pr, Mtot);
    k_ln2<<<dim3(2 * Pc, Bb), dim3(256), 0, stream>>>(zbuf, gW, lng, lnb, Wl, bl,
                                                      hiddb, leaves, pr,
                                                      HS.lvlOff[l]);
  }

  if (bfp) {
    k_gemm<1><<<dim3(NWG), dim3(256), 0, stream>>>(hiddb, Wt, bout, out, lgt,
                                                   ptile, Mrows);
    k_lse<<<dim3(Mrows), dim3(256), 0, stream>>>(ptile, st);
    k_norm_bf<<<dim3(16, Mrows), dim3(256), 0, stream>>>(lgt, out, st);
  } else {
    k_gemm<0><<<dim3(NWG), dim3(256), 0, stream>>>(hiddb, Wt, bout, out, lgt,
                                                   ptile, Mrows);
    k_lse<<<dim3(Mrows), dim3(256), 0, stream>>>(ptile, st);
    k_norm<<<dim3(32, Mrows), dim3(256), 0, stream>>>(out, st);
  }
  k_idx<<<dim3(1), dim3(256), 0, stream>>>(idxdst);
}